// Round 1
// baseline (551.737 us; speedup 1.0000x reference)
//
#include <hip/hip_runtime.h>

#define B_   256
#define L_   1024
#define H_   256   // DEC_H == ENC_D
#define EMB_ 128
#define OUT_ 172

typedef float f32x4 __attribute__((ext_vector_type(4)));
typedef __bf16 bf16x8 __attribute__((ext_vector_type(8)));
typedef unsigned short us8 __attribute__((ext_vector_type(8)));

static __device__ __forceinline__ unsigned short f2bf(float f) {
    unsigned u = __float_as_uint(f);
    u += 0x7fffu + ((u >> 16) & 1u);   // RNE
    return (unsigned short)(u >> 16);
}
static __device__ __forceinline__ float bf2f(unsigned short s) {
    return __uint_as_float(((unsigned)s) << 16);
}
static __device__ __forceinline__ float tanh_fast(float x) {
    // tanh(x) = 1 - 2/(e^{2x}+1); exact limits at +-inf
    float e = __expf(2.f * x);
    return 1.f - 2.f * __builtin_amdgcn_rcpf(e + 1.f);
}
static __device__ __forceinline__ float sigm_fast(float x) {
    return __builtin_amdgcn_rcpf(1.f + __expf(-x));
}

// ---------------------------------------------------------------- K1: gates
// gates[b, j] = b_ih[j]+b_hh[j] + sum_k inp[b,k]*W_ih[j,k] + sum_k h0[b,k]*W_hh[j,k]
// grid 64 blocks x 256 thr; block handles 4 b's, thread handles 4 gate rows (j, j+256, j+512, j+768)
__global__ __launch_bounds__(256) void k_gates(
    const float* __restrict__ h0, const float* __restrict__ o_t,
    const int* __restrict__ lasttarget, const float* __restrict__ emb,
    const float* __restrict__ W_ih, const float* __restrict__ W_hh,
    const float* __restrict__ b_ih, const float* __restrict__ b_hh,
    float* __restrict__ gates)
{
    const int bg  = blockIdx.x;     // 0..63
    const int tid = threadIdx.x;    // 0..255

    __shared__ __align__(16) float inp[4][384];
    __shared__ __align__(16) float h0s[4][256];

    for (int i = tid; i < 4 * 384; i += 256) {
        int bb = i / 384, k = i - bb * 384;
        int b = bg * 4 + bb;
        float v;
        if (k < EMB_) { int lt = lasttarget[b]; v = emb[lt * EMB_ + k]; }
        else          { v = o_t[b * H_ + (k - EMB_)]; }
        inp[bb][k] = v;
    }
    for (int i = tid; i < 4 * 256; i += 256) {
        int bb = i >> 8, k = i & 255;
        h0s[bb][k] = h0[(bg * 4 + bb) * H_ + k];
    }
    __syncthreads();

    float acc[4][4];  // [gate-part][bb]
    #pragma unroll
    for (int p = 0; p < 4; p++) {
        float bias = b_ih[p * 256 + tid] + b_hh[p * 256 + tid];
        #pragma unroll
        for (int bb = 0; bb < 4; bb++) acc[p][bb] = bias;
    }

    const float* wi0 = W_ih + (0   + tid) * 384;
    const float* wi1 = W_ih + (256 + tid) * 384;
    const float* wi2 = W_ih + (512 + tid) * 384;
    const float* wi3 = W_ih + (768 + tid) * 384;
    for (int k = 0; k < 384; k += 4) {
        float4 w0 = *(const float4*)(wi0 + k);
        float4 w1 = *(const float4*)(wi1 + k);
        float4 w2 = *(const float4*)(wi2 + k);
        float4 w3 = *(const float4*)(wi3 + k);
        #pragma unroll
        for (int bb = 0; bb < 4; bb++) {
            float4 iv = *(const float4*)&inp[bb][k];
            acc[0][bb] += w0.x*iv.x + w0.y*iv.y + w0.z*iv.z + w0.w*iv.w;
            acc[1][bb] += w1.x*iv.x + w1.y*iv.y + w1.z*iv.z + w1.w*iv.w;
            acc[2][bb] += w2.x*iv.x + w2.y*iv.y + w2.z*iv.z + w2.w*iv.w;
            acc[3][bb] += w3.x*iv.x + w3.y*iv.y + w3.z*iv.z + w3.w*iv.w;
        }
    }
    const float* wh0 = W_hh + (0   + tid) * 256;
    const float* wh1 = W_hh + (256 + tid) * 256;
    const float* wh2 = W_hh + (512 + tid) * 256;
    const float* wh3 = W_hh + (768 + tid) * 256;
    for (int k = 0; k < 256; k += 4) {
        float4 w0 = *(const float4*)(wh0 + k);
        float4 w1 = *(const float4*)(wh1 + k);
        float4 w2 = *(const float4*)(wh2 + k);
        float4 w3 = *(const float4*)(wh3 + k);
        #pragma unroll
        for (int bb = 0; bb < 4; bb++) {
            float4 hv = *(const float4*)&h0s[bb][k];
            acc[0][bb] += w0.x*hv.x + w0.y*hv.y + w0.z*hv.z + w0.w*hv.w;
            acc[1][bb] += w1.x*hv.x + w1.y*hv.y + w1.z*hv.z + w1.w*hv.w;
            acc[2][bb] += w2.x*hv.x + w2.y*hv.y + w2.z*hv.z + w2.w*hv.w;
            acc[3][bb] += w3.x*hv.x + w3.y*hv.y + w3.z*hv.z + w3.w*hv.w;
        }
    }
    #pragma unroll
    for (int bb = 0; bb < 4; bb++) {
        float* gp = gates + (bg * 4 + bb) * 1024;
        gp[tid]       = acc[0][bb];
        gp[256 + tid] = acc[1][bb];
        gp[512 + tid] = acc[2][bb];
        gp[768 + tid] = acc[3][bb];
    }
}

// ---------------------------------------------------------------- K2: LSTM pointwise + hW2
__global__ __launch_bounds__(256) void k_lstm(
    const float* __restrict__ gates, const float* __restrict__ c0,
    const float* __restrict__ W2, float* __restrict__ out, float* __restrict__ hW2)
{
    const int b = blockIdx.x, t = threadIdx.x;
    const float* g = gates + b * 1024;
    float gi = g[t], gf = g[256 + t], gg = g[512 + t], go = g[768 + t];
    float c = sigm_fast(gf) * c0[b * H_ + t] + sigm_fast(gi) * tanh_fast(gg);
    float h = sigm_fast(go) * tanh_fast(c);
    out[b * H_ + t]             = h;   // h_t
    out[B_ * H_ + b * H_ + t]   = c;   // c_t

    __shared__ __align__(16) float hs[256];
    hs[t] = h;
    __syncthreads();
    const float* w2 = W2 + t * 256;
    float a = 0.f;
    for (int k = 0; k < 256; k += 4) {
        float4 w = *(const float4*)(w2 + k);
        a += w.x*hs[k] + w.y*hs[k+1] + w.z*hs[k+2] + w.w*hs[k+3];
    }
    hW2[b * H_ + t] = a;
}

// ---------------------------------------------------------------- K3: fused attention
// per block: b = blk>>1, rows [half*512, half*512+512) of enc_out[b]
// one pass: u = enc @ W1^T + hW2 ; score = beta . tanh(u) ; w = exp(score)
// ctx_part = sum w*enc_row ; s_part = sum w   (softmax needs no max-shift: |score| <= ||beta||_1 < 2.6)
#define ROWSTR 264   // 256 bf16 + 8 pad (2-way LDS bank alias only)

__global__ __launch_bounds__(512, 4) void k_attn(
    const float* __restrict__ enc, const float* __restrict__ W1,
    const float* __restrict__ hW2, const float* __restrict__ beta,
    float* __restrict__ ctx_part, float* __restrict__ s_part)
{
    const int blk = blockIdx.x;
    const int b = blk >> 1, half = blk & 1;
    const int tid = threadIdx.x;
    const int wave = tid >> 6, lane = tid & 63;
    const int quad = lane >> 4, l15 = lane & 15;

    __shared__ __align__(16) unsigned short encs[2][16 * ROWSTR];
    __shared__ float sp[8][16];
    __shared__ float wexp[16];

    // W1 B-fragments in registers: wave covers output cols [wave*32, wave*32+32)
    bf16x8 wf[8][2];
    float hw2v[2], betav[2];
    #pragma unroll
    for (int nt = 0; nt < 2; nt++) {
        int n = wave * 32 + nt * 16 + l15;
        hw2v[nt]  = hW2[b * H_ + n];
        betav[nt] = beta[n];
        #pragma unroll
        for (int ks = 0; ks < 8; ks++) {
            const float* p = W1 + n * 256 + ks * 32 + quad * 8;
            float4 x0 = *(const float4*)p, x1 = *(const float4*)(p + 4);
            us8 v;
            v[0]=f2bf(x0.x); v[1]=f2bf(x0.y); v[2]=f2bf(x0.z); v[3]=f2bf(x0.w);
            v[4]=f2bf(x1.x); v[5]=f2bf(x1.y); v[6]=f2bf(x1.z); v[7]=f2bf(x1.w);
            wf[ks][nt] = __builtin_bit_cast(bf16x8, v);
        }
    }

    const float* encb = enc + (size_t)(b * L_ + half * 512) * H_;
    const int srow = tid >> 5, scol = (tid & 31) * 8;

    // prologue: stage tile 0 into buf 0
    {
        const float* p = encb + srow * 256 + scol;
        float4 x0 = *(const float4*)p, x1 = *(const float4*)(p + 4);
        us8 v;
        v[0]=f2bf(x0.x); v[1]=f2bf(x0.y); v[2]=f2bf(x0.z); v[3]=f2bf(x0.w);
        v[4]=f2bf(x1.x); v[5]=f2bf(x1.y); v[6]=f2bf(x1.z); v[7]=f2bf(x1.w);
        *(us8*)&encs[0][srow * ROWSTR + scol] = v;
    }
    __syncthreads();

    float ctx = 0.f, ssum = 0.f;

    for (int it = 0; it < 32; it++) {
        const int cur = it & 1;
        // phase 1: issue next tile's global loads (land in phase 3)
        float4 x0, x1;
        if (it < 31) {
            const float* p = encb + (it + 1) * 16 * 256 + srow * 256 + scol;
            x0 = *(const float4*)p; x1 = *(const float4*)(p + 4);
        }
        // MFMA: 16 rows x 32 cols per wave
        f32x4 acc0 = {0.f,0.f,0.f,0.f}, acc1 = {0.f,0.f,0.f,0.f};
        const unsigned short* arow = &encs[cur][l15 * ROWSTR + quad * 8];
        #pragma unroll
        for (int ks = 0; ks < 8; ks++) {
            bf16x8 a = __builtin_bit_cast(bf16x8, *(const us8*)(arow + ks * 32));
            acc0 = __builtin_amdgcn_mfma_f32_16x16x32_bf16(a, wf[ks][0], acc0, 0, 0, 0);
            acc1 = __builtin_amdgcn_mfma_f32_16x16x32_bf16(a, wf[ks][1], acc1, 0, 0, 0);
        }
        // score partials: row = quad*4+r, cols reduced over lane&15 then waves
        float p4[4];
        #pragma unroll
        for (int r = 0; r < 4; r++) {
            float t0 = tanh_fast(acc0[r] + hw2v[0]);
            float t1 = tanh_fast(acc1[r] + hw2v[1]);
            p4[r] = betav[0] * t0 + betav[1] * t1;
        }
        #pragma unroll
        for (int m = 1; m < 16; m <<= 1) {
            p4[0] += __shfl_xor(p4[0], m);
            p4[1] += __shfl_xor(p4[1], m);
            p4[2] += __shfl_xor(p4[2], m);
            p4[3] += __shfl_xor(p4[3], m);
        }
        if (l15 == 0) {
            #pragma unroll
            for (int r = 0; r < 4; r++) sp[wave][quad * 4 + r] = p4[r];
        }
        __syncthreads();               // A: sp visible
        if (tid < 16) {
            float sc = sp[0][tid] + sp[1][tid] + sp[2][tid] + sp[3][tid]
                     + sp[4][tid] + sp[5][tid] + sp[6][tid] + sp[7][tid];
            wexp[tid] = __expf(sc);
        }
        __syncthreads();               // B: wexp visible
        // phase 3: write next tile to other buffer; accumulate ctx from current
        if (it < 31) {
            us8 v;
            v[0]=f2bf(x0.x); v[1]=f2bf(x0.y); v[2]=f2bf(x0.z); v[3]=f2bf(x0.w);
            v[4]=f2bf(x1.x); v[5]=f2bf(x1.y); v[6]=f2bf(x1.z); v[7]=f2bf(x1.w);
            *(us8*)&encs[cur ^ 1][srow * ROWSTR + scol] = v;
        }
        if (tid < 256) {
            const unsigned short* col = &encs[cur][tid];
            float c = ctx;
            #pragma unroll
            for (int r = 0; r < 16; r++) c += wexp[r] * bf2f(col[r * ROWSTR]);
            ctx = c;
        }
        if (tid == 0) {
            float s2 = 0.f;
            #pragma unroll
            for (int r = 0; r < 16; r++) s2 += wexp[r];
            ssum += s2;
        }
        __syncthreads();               // C: buffers safe to swap
    }
    if (tid < 256) ctx_part[blk * 256 + tid] = ctx;
    if (tid == 0)  s_part[blk] = ssum;
}

// ---------------------------------------------------------------- K4: combine + o_new + logit
__global__ __launch_bounds__(256) void k_out(
    const float* __restrict__ ctx_part, const float* __restrict__ s_part,
    const float* __restrict__ W3, const float* __restrict__ W_out,
    float* __restrict__ out)
{
    const int b = blockIdx.x, t = threadIdx.x;
    __shared__ __align__(16) float ctxs[256];
    __shared__ __align__(16) float hs[256];
    __shared__ __align__(16) float osh[256];
    __shared__ float lsm[172];
    __shared__ float inv_s;

    float s = s_part[2 * b] + s_part[2 * b + 1];
    ctxs[t] = (ctx_part[(2 * b) * 256 + t] + ctx_part[(2 * b + 1) * 256 + t]) / s;
    hs[t] = out[b * H_ + t];   // h_t from K2
    __syncthreads();

    const float* w3 = W3 + t * 512;
    float a = 0.f;
    for (int k = 0; k < 256; k += 4) {
        float4 wA = *(const float4*)(w3 + k);
        float4 wB = *(const float4*)(w3 + 256 + k);
        a += wA.x*hs[k]   + wA.y*hs[k+1]   + wA.z*hs[k+2]   + wA.w*hs[k+3];
        a += wB.x*ctxs[k] + wB.y*ctxs[k+1] + wB.z*ctxs[k+2] + wB.w*ctxs[k+3];
    }
    float on = tanh_fast(a);
    out[2 * B_ * H_ + b * H_ + t] = on;  // o_new
    osh[t] = on;
    __syncthreads();

    if (t < OUT_) {
        const float* wo = W_out + t * 256;
        float a2 = 0.f;
        for (int k = 0; k < 256; k += 4) {
            float4 w = *(const float4*)(wo + k);
            a2 += w.x*osh[k] + w.y*osh[k+1] + w.z*osh[k+2] + w.w*osh[k+3];
        }
        lsm[t] = a2;
    }
    __syncthreads();
    if (t == 0) {
        float m = -1e30f;
        for (int i = 0; i < OUT_; i++) m = fmaxf(m, lsm[i]);
        float ss = 0.f;
        for (int i = 0; i < OUT_; i++) { float e = __expf(lsm[i] - m); lsm[i] = e; ss += e; }
        inv_s = 1.f / ss;
    }
    __syncthreads();
    if (t < OUT_) out[3 * B_ * H_ + b * OUT_ + t] = lsm[t] * inv_s;
}

// ---------------------------------------------------------------- host
extern "C" void kernel_launch(void* const* d_in, const int* in_sizes, int n_in,
                              void* d_out, int out_size, void* d_ws, size_t ws_size,
                              hipStream_t stream)
{
    const float* h0   = (const float*)d_in[0];
    const float* c0   = (const float*)d_in[1];
    const float* o_t  = (const float*)d_in[2];
    const float* enc  = (const float*)d_in[3];
    const int*   lt   = (const int*)  d_in[4];
    const float* emb  = (const float*)d_in[5];
    const float* W_ih = (const float*)d_in[6];
    const float* W_hh = (const float*)d_in[7];
    const float* b_ih = (const float*)d_in[8];
    const float* b_hh = (const float*)d_in[9];
    const float* W1   = (const float*)d_in[10];
    const float* W2   = (const float*)d_in[11];
    const float* W3   = (const float*)d_in[12];
    const float* Wo   = (const float*)d_in[13];
    const float* beta = (const float*)d_in[14];
    float* out = (float*)d_out;
    float* ws  = (float*)d_ws;

    float* gates    = ws;            // 256*1024
    float* hW2      = ws + 262144;   // 256*256
    float* ctx_part = ws + 327680;   // 512*256
    float* s_part   = ws + 458752;   // 512

    k_gates<<<64, 256, 0, stream>>>(h0, o_t, lt, emb, W_ih, W_hh, b_ih, b_hh, gates);
    k_lstm <<<256, 256, 0, stream>>>(gates, c0, W2, out, hW2);
    k_attn <<<512, 512, 0, stream>>>(enc, W1, hW2, beta, ctx_part, s_part);
    k_out  <<<256, 256, 0, stream>>>(ctx_part, s_part, W3, Wo, out);
}

// Round 2
// 466.103 us; speedup vs baseline: 1.1837x; 1.1837x over previous
//
#include <hip/hip_runtime.h>

#define B_   256
#define L_   1024
#define H_   256   // DEC_H == ENC_D
#define EMB_ 128
#define OUT_ 172

typedef float f32x4 __attribute__((ext_vector_type(4)));
typedef __bf16 bf16x8 __attribute__((ext_vector_type(8)));
typedef unsigned short us8 __attribute__((ext_vector_type(8)));

static __device__ __forceinline__ unsigned short f2bf(float f) {
    unsigned u = __float_as_uint(f);
    u += 0x7fffu + ((u >> 16) & 1u);   // RNE
    return (unsigned short)(u >> 16);
}
static __device__ __forceinline__ float bf2f(unsigned short s) {
    return __uint_as_float(((unsigned)s) << 16);
}
static __device__ __forceinline__ us8 cvt8(const float* __restrict__ p) {
    float4 x0 = *(const float4*)p, x1 = *(const float4*)(p + 4);
    us8 v;
    v[0]=f2bf(x0.x); v[1]=f2bf(x0.y); v[2]=f2bf(x0.z); v[3]=f2bf(x0.w);
    v[4]=f2bf(x1.x); v[5]=f2bf(x1.y); v[6]=f2bf(x1.z); v[7]=f2bf(x1.w);
    return v;
}
static __device__ __forceinline__ float tanh_fast(float x) {
    float e = __expf(2.f * x);
    return 1.f - 2.f * __builtin_amdgcn_rcpf(e + 1.f);
}
static __device__ __forceinline__ float sigm_fast(float x) {
    return __builtin_amdgcn_rcpf(1.f + __expf(-x));
}

// LDS tile row stride for 64x32 bf16 GEMM tiles (16B-aligned; minor conflicts ok)
#define TS 40

// ------------------------------------------------- K1: gates = [emb|o_t|h0] @ [W_ih|W_hh]^T + biases
// MFMA GEMM M=256 N=1024 K=640. grid 64 = 4 m-tiles x 16 n-tiles, 256 thr.
__global__ __launch_bounds__(256) void k_gates(
    const float* __restrict__ h0, const float* __restrict__ o_t,
    const int* __restrict__ lasttarget, const float* __restrict__ emb,
    const float* __restrict__ W_ih, const float* __restrict__ W_hh,
    const float* __restrict__ b_ih, const float* __restrict__ b_hh,
    float* __restrict__ gates)
{
    const int m0 = (blockIdx.x >> 4) * 64;
    const int n0 = (blockIdx.x & 15) * 64;
    const int tid = threadIdx.x;
    const int w = tid >> 6, lane = tid & 63, quad = lane >> 4, l15 = lane & 15;

    __shared__ __align__(16) unsigned short As[64 * TS];
    __shared__ __align__(16) unsigned short Bs[64 * TS];

    float bias[4];
    #pragma unroll
    for (int nt = 0; nt < 4; nt++) {
        int n = n0 + nt * 16 + l15;
        bias[nt] = b_ih[n] + b_hh[n];
    }

    f32x4 acc[4] = {{0,0,0,0},{0,0,0,0},{0,0,0,0},{0,0,0,0}};
    const int sm = tid >> 2, sk8 = (tid & 3) * 8;
    const int lt = lasttarget[m0 + sm];

    for (int kc = 0; kc < 20; kc++) {
        const int k = kc * 32 + sk8;
        // A gather: [emb | o_t | h0] (k-chunk never straddles 128/384 boundaries)
        const float* ap;
        if (k < 128)      ap = emb + lt * EMB_ + k;
        else if (k < 384) ap = o_t + (m0 + sm) * H_ + (k - 128);
        else              ap = h0  + (m0 + sm) * H_ + (k - 384);
        *(us8*)&As[sm * TS + sk8] = cvt8(ap);
        // B: W row j = n0+sm; [W_ih | W_hh]
        const int j = n0 + sm;
        const float* bp = (k < 384) ? (W_ih + j * 384 + k) : (W_hh + j * 256 + (k - 384));
        *(us8*)&Bs[sm * TS + sk8] = cvt8(bp);
        __syncthreads();
        bf16x8 a = __builtin_bit_cast(bf16x8, *(const us8*)&As[(w * 16 + l15) * TS + quad * 8]);
        #pragma unroll
        for (int nt = 0; nt < 4; nt++) {
            bf16x8 b = __builtin_bit_cast(bf16x8, *(const us8*)&Bs[(nt * 16 + l15) * TS + quad * 8]);
            acc[nt] = __builtin_amdgcn_mfma_f32_16x16x32_bf16(a, b, acc[nt], 0, 0, 0);
        }
        __syncthreads();
    }
    #pragma unroll
    for (int nt = 0; nt < 4; nt++)
        #pragma unroll
        for (int r = 0; r < 4; r++)
            gates[(m0 + w * 16 + quad * 4 + r) * 1024 + n0 + nt * 16 + l15] = acc[nt][r] + bias[nt];
}

// ------------------------------------------------- K2: LSTM pointwise; writes h_t,c_t (f32 out) + h bf16 into A3 left half
__global__ __launch_bounds__(256) void k_lstm(
    const float* __restrict__ gates, const float* __restrict__ c0,
    float* __restrict__ out, unsigned short* __restrict__ A3u)
{
    const int b = blockIdx.x, t = threadIdx.x;
    const float* g = gates + b * 1024;
    float gi = g[t], gf = g[256 + t], gg = g[512 + t], go = g[768 + t];
    float c = sigm_fast(gf) * c0[b * H_ + t] + sigm_fast(gi) * tanh_fast(gg);
    float h = sigm_fast(go) * tanh_fast(c);
    out[b * H_ + t]           = h;   // h_t
    out[B_ * H_ + b * H_ + t] = c;   // c_t
    A3u[b * 512 + t] = f2bf(h);      // bf16 h for hW2 / W3 GEMMs
}

// ------------------------------------------------- K3: hW2 = h @ W2^T (MFMA, M=256 N=256 K=256), grid 16
__global__ __launch_bounds__(256) void k_hw2(
    const unsigned short* __restrict__ A3u, const float* __restrict__ W2,
    float* __restrict__ hW2)
{
    const int m0 = (blockIdx.x >> 2) * 64;
    const int n0 = (blockIdx.x & 3) * 64;
    const int tid = threadIdx.x;
    const int w = tid >> 6, lane = tid & 63, quad = lane >> 4, l15 = lane & 15;
    __shared__ __align__(16) unsigned short As[64 * TS];
    __shared__ __align__(16) unsigned short Bs[64 * TS];
    f32x4 acc[4] = {{0,0,0,0},{0,0,0,0},{0,0,0,0},{0,0,0,0}};
    const int sm = tid >> 2, sk8 = (tid & 3) * 8;
    for (int kc = 0; kc < 8; kc++) {
        const int k = kc * 32 + sk8;
        *(us8*)&As[sm * TS + sk8] = *(const us8*)&A3u[(m0 + sm) * 512 + k];
        *(us8*)&Bs[sm * TS + sk8] = cvt8(W2 + (n0 + sm) * 256 + k);
        __syncthreads();
        bf16x8 a = __builtin_bit_cast(bf16x8, *(const us8*)&As[(w * 16 + l15) * TS + quad * 8]);
        #pragma unroll
        for (int nt = 0; nt < 4; nt++) {
            bf16x8 b = __builtin_bit_cast(bf16x8, *(const us8*)&Bs[(nt * 16 + l15) * TS + quad * 8]);
            acc[nt] = __builtin_amdgcn_mfma_f32_16x16x32_bf16(a, b, acc[nt], 0, 0, 0);
        }
        __syncthreads();
    }
    #pragma unroll
    for (int nt = 0; nt < 4; nt++)
        #pragma unroll
        for (int r = 0; r < 4; r++)
            hW2[(m0 + w * 16 + quad * 4 + r) * 256 + n0 + nt * 16 + l15] = acc[nt][r];
}

// ------------------------------------------------- K4: fused attention, one block per batch b
// score = beta . tanh(enc@W1^T + hW2); w=exp(score) (|score|<2.6 -> no max shift)
// ctx = sum w*enc / sum w, written as bf16 into A3 right half
#define ROWSTR 264   // 256 bf16 + 8 pad

__global__ __launch_bounds__(512, 2) void k_attn(
    const float* __restrict__ enc, const float* __restrict__ W1,
    const float* __restrict__ hW2, const float* __restrict__ beta,
    unsigned short* __restrict__ A3u)
{
    const int b = blockIdx.x;
    const int tid = threadIdx.x;
    const int wave = tid >> 6, lane = tid & 63;
    const int quad = lane >> 4, l15 = lane & 15;

    __shared__ __align__(16) unsigned short encs[2][16 * ROWSTR];
    __shared__ float sp[8][16];
    __shared__ float wexp[16];
    __shared__ float2 cr[512];
    __shared__ float ssum_s;

    // W1 B-fragments resident: wave covers cols [wave*32, wave*32+32)
    bf16x8 wf[8][2];
    float hw2v[2], betav[2];
    #pragma unroll
    for (int nt = 0; nt < 2; nt++) {
        int n = wave * 32 + nt * 16 + l15;
        hw2v[nt]  = hW2[b * H_ + n];
        betav[nt] = beta[n];
        #pragma unroll
        for (int ks = 0; ks < 8; ks++)
            wf[ks][nt] = __builtin_bit_cast(bf16x8, cvt8(W1 + n * 256 + ks * 32 + quad * 8));
    }

    const float* encb = enc + (size_t)b * L_ * H_;
    const int srow = tid >> 5, scol = (tid & 31) * 8;

    // prologue: tile 0 -> buf 0
    *(us8*)&encs[0][srow * ROWSTR + scol] = cvt8(encb + srow * 256 + scol);
    __syncthreads();

    const int cp = tid & 127, q = tid >> 7;   // ctx: col-pair, row-quarter
    float2 ctx2 = {0.f, 0.f};
    float ssum = 0.f;

    for (int it = 0; it < 64; it++) {
        const int cur = it & 1;
        float4 x0, x1;
        if (it < 63) {   // issue next tile's loads now; land in phase 3
            const float* p = encb + (it + 1) * 16 * 256 + srow * 256 + scol;
            x0 = *(const float4*)p; x1 = *(const float4*)(p + 4);
        }
        // MFMA: u-tile 16 rows x 32 cols per wave
        f32x4 acc0 = {0,0,0,0}, acc1 = {0,0,0,0};
        const unsigned short* arow = &encs[cur][l15 * ROWSTR + quad * 8];
        #pragma unroll
        for (int ks = 0; ks < 8; ks++) {
            bf16x8 a = __builtin_bit_cast(bf16x8, *(const us8*)(arow + ks * 32));
            acc0 = __builtin_amdgcn_mfma_f32_16x16x32_bf16(a, wf[ks][0], acc0, 0, 0, 0);
            acc1 = __builtin_amdgcn_mfma_f32_16x16x32_bf16(a, wf[ks][1], acc1, 0, 0, 0);
        }
        float p4[4];
        #pragma unroll
        for (int r = 0; r < 4; r++) {
            float t0 = tanh_fast(acc0[r] + hw2v[0]);
            float t1 = tanh_fast(acc1[r] + hw2v[1]);
            p4[r] = betav[0] * t0 + betav[1] * t1;
        }
        #pragma unroll
        for (int m = 1; m < 16; m <<= 1) {
            p4[0] += __shfl_xor(p4[0], m);
            p4[1] += __shfl_xor(p4[1], m);
            p4[2] += __shfl_xor(p4[2], m);
            p4[3] += __shfl_xor(p4[3], m);
        }
        if (l15 == 0) {
            #pragma unroll
            for (int r = 0; r < 4; r++) sp[wave][quad * 4 + r] = p4[r];
        }
        __syncthreads();               // A: sp visible
        if (tid < 16) {
            float sc = sp[0][tid] + sp[1][tid] + sp[2][tid] + sp[3][tid]
                     + sp[4][tid] + sp[5][tid] + sp[6][tid] + sp[7][tid];
            wexp[tid] = __expf(sc);
        }
        __syncthreads();               // B: wexp visible
        // stage next tile into other buffer
        if (it < 63) {
            us8 v;
            v[0]=f2bf(x0.x); v[1]=f2bf(x0.y); v[2]=f2bf(x0.z); v[3]=f2bf(x0.w);
            v[4]=f2bf(x1.x); v[5]=f2bf(x1.y); v[6]=f2bf(x1.z); v[7]=f2bf(x1.w);
            *(us8*)&encs[cur ^ 1][srow * ROWSTR + scol] = v;
        }
        // ctx accumulate: all 512 threads; thread covers cols {2cp,2cp+1}, rows q*4..q*4+3
        {
            const unsigned* base = (const unsigned*)&encs[cur][0];
            float cx = ctx2.x, cy = ctx2.y;
            #pragma unroll
            for (int r = 0; r < 4; r++) {
                const int row = q * 4 + r;
                unsigned u = base[row * (ROWSTR / 2) + cp];
                float wv = wexp[row];   // wave-uniform -> LDS broadcast
                cx += wv * __uint_as_float(u << 16);
                cy += wv * __uint_as_float(u & 0xffff0000u);
            }
            ctx2.x = cx; ctx2.y = cy;
        }
        if (tid == 0) {
            float s2 = 0.f;
            #pragma unroll
            for (int r = 0; r < 16; r++) s2 += wexp[r];
            ssum += s2;
        }
        __syncthreads();               // C: buffer safe to overwrite
    }
    if (tid == 0) ssum_s = ssum;
    cr[tid] = ctx2;
    __syncthreads();
    if (tid < 128) {
        float2 a0 = cr[tid], a1 = cr[tid + 128], a2 = cr[tid + 256], a3 = cr[tid + 384];
        float inv = __builtin_amdgcn_rcpf(ssum_s);
        float cx = (a0.x + a1.x + a2.x + a3.x) * inv;
        float cy = (a0.y + a1.y + a2.y + a3.y) * inv;
        unsigned pack = (unsigned)f2bf(cx) | ((unsigned)f2bf(cy) << 16);
        ((unsigned*)A3u)[b * 256 + 128 + tid] = pack;   // cols 256+2t, 256+2t+1
    }
}

// ------------------------------------------------- K5: o_new = tanh([h|ctx] @ W3^T)  (M=256 N=256 K=512), grid 16
__global__ __launch_bounds__(256) void k_out3(
    const unsigned short* __restrict__ A3u, const float* __restrict__ W3,
    float* __restrict__ out, unsigned short* __restrict__ A4u)
{
    const int m0 = (blockIdx.x >> 2) * 64;
    const int n0 = (blockIdx.x & 3) * 64;
    const int tid = threadIdx.x;
    const int w = tid >> 6, lane = tid & 63, quad = lane >> 4, l15 = lane & 15;
    __shared__ __align__(16) unsigned short As[64 * TS];
    __shared__ __align__(16) unsigned short Bs[64 * TS];
    f32x4 acc[4] = {{0,0,0,0},{0,0,0,0},{0,0,0,0},{0,0,0,0}};
    const int sm = tid >> 2, sk8 = (tid & 3) * 8;
    for (int kc = 0; kc < 16; kc++) {
        const int k = kc * 32 + sk8;
        *(us8*)&As[sm * TS + sk8] = *(const us8*)&A3u[(m0 + sm) * 512 + k];
        *(us8*)&Bs[sm * TS + sk8] = cvt8(W3 + (n0 + sm) * 512 + k);
        __syncthreads();
        bf16x8 a = __builtin_bit_cast(bf16x8, *(const us8*)&As[(w * 16 + l15) * TS + quad * 8]);
        #pragma unroll
        for (int nt = 0; nt < 4; nt++) {
            bf16x8 b = __builtin_bit_cast(bf16x8, *(const us8*)&Bs[(nt * 16 + l15) * TS + quad * 8]);
            acc[nt] = __builtin_amdgcn_mfma_f32_16x16x32_bf16(a, b, acc[nt], 0, 0, 0);
        }
        __syncthreads();
    }
    #pragma unroll
    for (int nt = 0; nt < 4; nt++)
        #pragma unroll
        for (int r = 0; r < 4; r++) {
            int row = m0 + w * 16 + quad * 4 + r, col = n0 + nt * 16 + l15;
            float o = tanh_fast(acc[nt][r]);
            out[2 * B_ * H_ + row * 256 + col] = o;   // o_new
            A4u[row * 256 + col] = f2bf(o);
        }
}

// ------------------------------------------------- K6: logit = softmax(o_new @ W_out^T), grid 4 (64 rows each)
__global__ __launch_bounds__(256) void k_logit(
    const unsigned short* __restrict__ A4u, const float* __restrict__ W_out,
    float* __restrict__ out)
{
    const int m0 = blockIdx.x * 64;
    const int tid = threadIdx.x;
    const int w = tid >> 6, lane = tid & 63, quad = lane >> 4, l15 = lane & 15;
    __shared__ __align__(16) unsigned short As[64 * TS];
    __shared__ __align__(16) unsigned short Bs[192 * TS];
    __shared__ float lg[64][196];
    f32x4 acc[12];
    #pragma unroll
    for (int nt = 0; nt < 12; nt++) acc[nt] = (f32x4){0,0,0,0};
    const int sm = tid >> 2, sk8 = (tid & 3) * 8;
    for (int kc = 0; kc < 8; kc++) {
        const int k = kc * 32 + sk8;
        *(us8*)&As[sm * TS + sk8] = *(const us8*)&A4u[(m0 + sm) * 256 + k];
        #pragma unroll
        for (int rr = 0; rr < 3; rr++) {
            int j = rr * 64 + sm;
            us8 v = {0,0,0,0,0,0,0,0};
            if (j < OUT_) v = cvt8(W_out + j * 256 + k);
            *(us8*)&Bs[j * TS + sk8] = v;
        }
        __syncthreads();
        bf16x8 a = __builtin_bit_cast(bf16x8, *(const us8*)&As[(w * 16 + l15) * TS + quad * 8]);
        #pragma unroll
        for (int nt = 0; nt < 12; nt++) {
            bf16x8 b = __builtin_bit_cast(bf16x8, *(const us8*)&Bs[(nt * 16 + l15) * TS + quad * 8]);
            acc[nt] = __builtin_amdgcn_mfma_f32_16x16x32_bf16(a, b, acc[nt], 0, 0, 0);
        }
        __syncthreads();
    }
    #pragma unroll
    for (int nt = 0; nt < 12; nt++)
        #pragma unroll
        for (int r = 0; r < 4; r++)
            lg[w * 16 + quad * 4 + r][nt * 16 + l15] = acc[nt][r];
    __syncthreads();
    // row softmax: 4 threads per row, 43 cols each (4*43 = 172)
    const int m = tid >> 2, p = tid & 3;
    const int cb = p * 43;
    float mx = -1e30f;
    for (int c = 0; c < 43; c++) mx = fmaxf(mx, lg[m][cb + c]);
    mx = fmaxf(mx, __shfl_xor(mx, 1));
    mx = fmaxf(mx, __shfl_xor(mx, 2));
    float s = 0.f;
    for (int c = 0; c < 43; c++) { float e = __expf(lg[m][cb + c] - mx); lg[m][cb + c] = e; s += e; }
    s += __shfl_xor(s, 1);
    s += __shfl_xor(s, 2);
    float inv = 1.f / s;
    for (int c = 0; c < 43; c++)
        out[3 * B_ * H_ + (m0 + m) * OUT_ + cb + c] = lg[m][cb + c] * inv;
}

// ------------------------------------------------- host
extern "C" void kernel_launch(void* const* d_in, const int* in_sizes, int n_in,
                              void* d_out, int out_size, void* d_ws, size_t ws_size,
                              hipStream_t stream)
{
    const float* h0   = (const float*)d_in[0];
    const float* c0   = (const float*)d_in[1];
    const float* o_t  = (const float*)d_in[2];
    const float* enc  = (const float*)d_in[3];
    const int*   lt   = (const int*)  d_in[4];
    const float* emb  = (const float*)d_in[5];
    const float* W_ih = (const float*)d_in[6];
    const float* W_hh = (const float*)d_in[7];
    const float* b_ih = (const float*)d_in[8];
    const float* b_hh = (const float*)d_in[9];
    const float* W1   = (const float*)d_in[10];
    const float* W2   = (const float*)d_in[11];
    const float* W3   = (const float*)d_in[12];
    const float* Wo   = (const float*)d_in[13];
    const float* beta = (const float*)d_in[14];
    float* out = (float*)d_out;
    float* ws  = (float*)d_ws;

    float*          gates = ws;                                  // 256*1024 f32
    float*          hW2   = ws + 262144;                         // 256*256 f32
    unsigned short* A3u   = (unsigned short*)(ws + 327680);      // 256*512 bf16 = [h | ctx]
    unsigned short* A4u   = (unsigned short*)(ws + 393216);      // 256*256 bf16 o_new

    k_gates<<<64, 256, 0, stream>>>(h0, o_t, lt, emb, W_ih, W_hh, b_ih, b_hh, gates);
    k_lstm <<<256, 256, 0, stream>>>(gates, c0, out, A3u);
    k_hw2  <<<16, 256, 0, stream>>>(A3u, W2, hW2);
    k_attn <<<256, 512, 0, stream>>>(enc, W1, hW2, beta, A3u);
    k_out3 <<<16, 256, 0, stream>>>(A3u, W3, out, A4u);
    k_logit<<<4, 256, 0, stream>>>(A4u, Wo, out);
}

// Round 3
// 464.098 us; speedup vs baseline: 1.1888x; 1.0043x over previous
//
#include <hip/hip_runtime.h>

#define B_   256
#define L_   1024
#define H_   256   // DEC_H == ENC_D
#define EMB_ 128
#define OUT_ 172

typedef float f32x4 __attribute__((ext_vector_type(4)));
typedef __bf16 bf16x8 __attribute__((ext_vector_type(8)));
typedef unsigned short us8 __attribute__((ext_vector_type(8)));

static __device__ __forceinline__ unsigned short f2bf(float f) {
    unsigned u = __float_as_uint(f);
    u += 0x7fffu + ((u >> 16) & 1u);   // RNE
    return (unsigned short)(u >> 16);
}
static __device__ __forceinline__ float bf2f(unsigned short s) {
    return __uint_as_float(((unsigned)s) << 16);
}
static __device__ __forceinline__ us8 cvt8(const float* __restrict__ p) {
    float4 x0 = *(const float4*)p, x1 = *(const float4*)(p + 4);
    us8 v;
    v[0]=f2bf(x0.x); v[1]=f2bf(x0.y); v[2]=f2bf(x0.z); v[3]=f2bf(x0.w);
    v[4]=f2bf(x1.x); v[5]=f2bf(x1.y); v[6]=f2bf(x1.z); v[7]=f2bf(x1.w);
    return v;
}
static __device__ __forceinline__ float tanh_fast(float x) {
    float e = __expf(2.f * x);
    return 1.f - 2.f * __builtin_amdgcn_rcpf(e + 1.f);
}
static __device__ __forceinline__ float sigm_fast(float x) {
    return __builtin_amdgcn_rcpf(1.f + __expf(-x));
}

// LDS tile row stride for 64x32 bf16 GEMM tiles (16B-aligned; minor conflicts ok)
#define TS 40

// ------------------------------------------------- K1: gates = [emb|o_t|h0] @ [W_ih|W_hh]^T + biases
__global__ __launch_bounds__(256) void k_gates(
    const float* __restrict__ h0, const float* __restrict__ o_t,
    const int* __restrict__ lasttarget, const float* __restrict__ emb,
    const float* __restrict__ W_ih, const float* __restrict__ W_hh,
    const float* __restrict__ b_ih, const float* __restrict__ b_hh,
    float* __restrict__ gates)
{
    const int m0 = (blockIdx.x >> 4) * 64;
    const int n0 = (blockIdx.x & 15) * 64;
    const int tid = threadIdx.x;
    const int w = tid >> 6, lane = tid & 63, quad = lane >> 4, l15 = lane & 15;

    __shared__ __align__(16) unsigned short As[64 * TS];
    __shared__ __align__(16) unsigned short Bs[64 * TS];

    float bias[4];
    #pragma unroll
    for (int nt = 0; nt < 4; nt++) {
        int n = n0 + nt * 16 + l15;
        bias[nt] = b_ih[n] + b_hh[n];
    }

    f32x4 acc[4] = {{0,0,0,0},{0,0,0,0},{0,0,0,0},{0,0,0,0}};
    const int sm = tid >> 2, sk8 = (tid & 3) * 8;
    const int lt = lasttarget[m0 + sm];

    for (int kc = 0; kc < 20; kc++) {
        const int k = kc * 32 + sk8;
        const float* ap;
        if (k < 128)      ap = emb + lt * EMB_ + k;
        else if (k < 384) ap = o_t + (m0 + sm) * H_ + (k - 128);
        else              ap = h0  + (m0 + sm) * H_ + (k - 384);
        *(us8*)&As[sm * TS + sk8] = cvt8(ap);
        const int j = n0 + sm;
        const float* bp = (k < 384) ? (W_ih + j * 384 + k) : (W_hh + j * 256 + (k - 384));
        *(us8*)&Bs[sm * TS + sk8] = cvt8(bp);
        __syncthreads();
        bf16x8 a = __builtin_bit_cast(bf16x8, *(const us8*)&As[(w * 16 + l15) * TS + quad * 8]);
        #pragma unroll
        for (int nt = 0; nt < 4; nt++) {
            bf16x8 b = __builtin_bit_cast(bf16x8, *(const us8*)&Bs[(nt * 16 + l15) * TS + quad * 8]);
            acc[nt] = __builtin_amdgcn_mfma_f32_16x16x32_bf16(a, b, acc[nt], 0, 0, 0);
        }
        __syncthreads();
    }
    #pragma unroll
    for (int nt = 0; nt < 4; nt++)
        #pragma unroll
        for (int r = 0; r < 4; r++)
            gates[(m0 + w * 16 + quad * 4 + r) * 1024 + n0 + nt * 16 + l15] = acc[nt][r] + bias[nt];
}

// ------------------------------------------------- K2: LSTM pointwise
__global__ __launch_bounds__(256) void k_lstm(
    const float* __restrict__ gates, const float* __restrict__ c0,
    float* __restrict__ out, unsigned short* __restrict__ A3u)
{
    const int b = blockIdx.x, t = threadIdx.x;
    const float* g = gates + b * 1024;
    float gi = g[t], gf = g[256 + t], gg = g[512 + t], go = g[768 + t];
    float c = sigm_fast(gf) * c0[b * H_ + t] + sigm_fast(gi) * tanh_fast(gg);
    float h = sigm_fast(go) * tanh_fast(c);
    out[b * H_ + t]           = h;   // h_t
    out[B_ * H_ + b * H_ + t] = c;   // c_t
    A3u[b * 256 + t] = f2bf(h);      // bf16 h for hW2 / W3 GEMMs
}

// ------------------------------------------------- K3: hW2 = h @ W2^T (M=256 N=256 K=256), grid 16
__global__ __launch_bounds__(256) void k_hw2(
    const unsigned short* __restrict__ A3u, const float* __restrict__ W2,
    float* __restrict__ hW2)
{
    const int m0 = (blockIdx.x >> 2) * 64;
    const int n0 = (blockIdx.x & 3) * 64;
    const int tid = threadIdx.x;
    const int w = tid >> 6, lane = tid & 63, quad = lane >> 4, l15 = lane & 15;
    __shared__ __align__(16) unsigned short As[64 * TS];
    __shared__ __align__(16) unsigned short Bs[64 * TS];
    f32x4 acc[4] = {{0,0,0,0},{0,0,0,0},{0,0,0,0},{0,0,0,0}};
    const int sm = tid >> 2, sk8 = (tid & 3) * 8;
    for (int kc = 0; kc < 8; kc++) {
        const int k = kc * 32 + sk8;
        *(us8*)&As[sm * TS + sk8] = *(const us8*)&A3u[(m0 + sm) * 256 + k];
        *(us8*)&Bs[sm * TS + sk8] = cvt8(W2 + (n0 + sm) * 256 + k);
        __syncthreads();
        bf16x8 a = __builtin_bit_cast(bf16x8, *(const us8*)&As[(w * 16 + l15) * TS + quad * 8]);
        #pragma unroll
        for (int nt = 0; nt < 4; nt++) {
            bf16x8 b = __builtin_bit_cast(bf16x8, *(const us8*)&Bs[(nt * 16 + l15) * TS + quad * 8]);
            acc[nt] = __builtin_amdgcn_mfma_f32_16x16x32_bf16(a, b, acc[nt], 0, 0, 0);
        }
        __syncthreads();
    }
    #pragma unroll
    for (int nt = 0; nt < 4; nt++)
        #pragma unroll
        for (int r = 0; r < 4; r++)
            hW2[(m0 + w * 16 + quad * 4 + r) * 256 + n0 + nt * 16 + l15] = acc[nt][r];
}

// ------------------------------------------------- K4: fused attention, 2 blocks per batch (512 rows each)
// 2 blocks/CU; triple-buffered enc tiles (prefetch distance 2); 2 barriers/iter.
// score = beta . tanh(enc@W1^T + hW2); w=exp(score) (|score| <= ||beta||_1 < 2.6 -> no max shift)
// outputs f32 partials: ctx_part[blk][256], s_part[blk]
#define ROWSTR 264   // 256 bf16 + 8 pad

__global__ __launch_bounds__(512, 2) void k_attn(
    const float* __restrict__ enc, const float* __restrict__ W1,
    const float* __restrict__ hW2, const float* __restrict__ beta,
    float* __restrict__ ctx_part, float* __restrict__ s_part)
{
    const int blk = blockIdx.x;
    const int b = blk >> 1, half = blk & 1;
    const int tid = threadIdx.x;
    const int wave = tid >> 6, lane = tid & 63;
    const int quad = lane >> 4, l15 = lane & 15;

    __shared__ __align__(16) unsigned short encs[3][16 * ROWSTR];
    __shared__ float sp[2][8][16];
    __shared__ float wexp[2][16];
    __shared__ float2 cr[512];

    // W1 B-fragments resident: wave covers cols [wave*32, wave*32+32)
    bf16x8 wf[8][2];
    float hw2v[2], betav[2];
    #pragma unroll
    for (int nt = 0; nt < 2; nt++) {
        int n = wave * 32 + nt * 16 + l15;
        hw2v[nt]  = hW2[b * H_ + n];
        betav[nt] = beta[n];
        #pragma unroll
        for (int ks = 0; ks < 8; ks++)
            wf[ks][nt] = __builtin_bit_cast(bf16x8, cvt8(W1 + n * 256 + ks * 32 + quad * 8));
    }

    const float* encb = enc + ((size_t)b * L_ + half * 512) * H_;
    const int srow = tid >> 5, scol = (tid & 31) * 8;

    // prologue: tile 0 -> buf 0; tile 1 -> regs
    *(us8*)&encs[0][srow * ROWSTR + scol] = cvt8(encb + srow * 256 + scol);
    float4 x0, x1;
    {
        const float* p = encb + 16 * 256 + srow * 256 + scol;
        x0 = *(const float4*)p; x1 = *(const float4*)(p + 4);
    }
    __syncthreads();

    const int cp = tid & 127, q = tid >> 7;   // ctx: col-pair, row-quarter
    float2 ctx2 = {0.f, 0.f};
    float ssum = 0.f;

    for (int it = 0; it < 32; it++) {
        const int cur = it % 3;
        const int nxt = (it + 1) % 3;
        const int par = it & 1;
        // issue loads for tile it+2 (consumed next iteration's LDS-write)
        float4 y0 = {0,0,0,0}, y1 = {0,0,0,0};
        if (it < 30) {
            const float* p = encb + (it + 2) * 16 * 256 + srow * 256 + scol;
            y0 = *(const float4*)p; y1 = *(const float4*)(p + 4);
        }
        // MFMA: u-tile 16 rows x 32 cols per wave, from buf cur
        f32x4 acc0 = {0,0,0,0}, acc1 = {0,0,0,0};
        const unsigned short* arow = &encs[cur][l15 * ROWSTR + quad * 8];
        #pragma unroll
        for (int ks = 0; ks < 8; ks++) {
            bf16x8 a = __builtin_bit_cast(bf16x8, *(const us8*)(arow + ks * 32));
            acc0 = __builtin_amdgcn_mfma_f32_16x16x32_bf16(a, wf[ks][0], acc0, 0, 0, 0);
            acc1 = __builtin_amdgcn_mfma_f32_16x16x32_bf16(a, wf[ks][1], acc1, 0, 0, 0);
        }
        // write tile it+1 (regs, loaded last iter) into buf nxt
        if (it < 31) {
            us8 v;
            v[0]=f2bf(x0.x); v[1]=f2bf(x0.y); v[2]=f2bf(x0.z); v[3]=f2bf(x0.w);
            v[4]=f2bf(x1.x); v[5]=f2bf(x1.y); v[6]=f2bf(x1.z); v[7]=f2bf(x1.w);
            *(us8*)&encs[nxt][srow * ROWSTR + scol] = v;
        }
        // score partials
        float p4[4];
        #pragma unroll
        for (int r = 0; r < 4; r++) {
            float t0 = tanh_fast(acc0[r] + hw2v[0]);
            float t1 = tanh_fast(acc1[r] + hw2v[1]);
            p4[r] = betav[0] * t0 + betav[1] * t1;
        }
        #pragma unroll
        for (int m = 1; m < 16; m <<= 1) {
            p4[0] += __shfl_xor(p4[0], m);
            p4[1] += __shfl_xor(p4[1], m);
            p4[2] += __shfl_xor(p4[2], m);
            p4[3] += __shfl_xor(p4[3], m);
        }
        if (l15 == 0) {
            #pragma unroll
            for (int r = 0; r < 4; r++) sp[par][wave][quad * 4 + r] = p4[r];
        }
        __syncthreads();               // A: sp + buf nxt visible
        if (tid < 16) {
            float sc = sp[par][0][tid] + sp[par][1][tid] + sp[par][2][tid] + sp[par][3][tid]
                     + sp[par][4][tid] + sp[par][5][tid] + sp[par][6][tid] + sp[par][7][tid];
            wexp[par][tid] = __expf(sc);
        }
        __syncthreads();               // B: wexp visible
        // ctx accumulate from buf cur: thread covers cols {2cp,2cp+1}, rows q*4..q*4+3
        {
            const unsigned* base = (const unsigned*)&encs[cur][0];
            float cx = ctx2.x, cy = ctx2.y;
            #pragma unroll
            for (int r = 0; r < 4; r++) {
                const int row = q * 4 + r;
                unsigned u = base[row * (ROWSTR / 2) + cp];
                float wv = wexp[par][row];   // wave-uniform -> broadcast
                cx += wv * __uint_as_float(u << 16);
                cy += wv * __uint_as_float(u & 0xffff0000u);
            }
            ctx2.x = cx; ctx2.y = cy;
        }
        if (tid == 0) {
            float s2 = 0.f;
            #pragma unroll
            for (int r = 0; r < 16; r++) s2 += wexp[par][r];
            ssum += s2;
        }
        // rotate prefetch regs
        x0 = y0; x1 = y1;
    }
    cr[tid] = ctx2;
    __syncthreads();
    if (tid == 0) s_part[blk] = ssum;
    if (tid < 128) {
        float2 a0 = cr[tid], a1 = cr[tid + 128], a2 = cr[tid + 256], a3 = cr[tid + 384];
        float2 o;
        o.x = a0.x + a1.x + a2.x + a3.x;
        o.y = a0.y + a1.y + a2.y + a3.y;
        ((float2*)ctx_part)[blk * 128 + tid] = o;   // cols 2t, 2t+1 (unnormalized)
    }
}

// ------------------------------------------------- K5: o_new = tanh([h|ctx] @ W3^T)  (M=256 N=256 K=512), grid 16
// ctx combine (2 halves + 1/s normalize) fused into A-staging.
__global__ __launch_bounds__(256) void k_out3(
    const unsigned short* __restrict__ A3u, const float* __restrict__ ctx_part,
    const float* __restrict__ s_part, const float* __restrict__ W3,
    float* __restrict__ out, unsigned short* __restrict__ A4u)
{
    const int m0 = (blockIdx.x >> 2) * 64;
    const int n0 = (blockIdx.x & 3) * 64;
    const int tid = threadIdx.x;
    const int w = tid >> 6, lane = tid & 63, quad = lane >> 4, l15 = lane & 15;
    __shared__ __align__(16) unsigned short As[64 * TS];
    __shared__ __align__(16) unsigned short Bs[64 * TS];
    f32x4 acc[4] = {{0,0,0,0},{0,0,0,0},{0,0,0,0},{0,0,0,0}};
    const int sm = tid >> 2, sk8 = (tid & 3) * 8;
    const int bb = m0 + sm;
    const float inv = 1.f / (s_part[2 * bb] + s_part[2 * bb + 1]);
    for (int kc = 0; kc < 16; kc++) {
        const int k = kc * 32 + sk8;
        if (k < 256) {
            *(us8*)&As[sm * TS + sk8] = *(const us8*)&A3u[bb * 256 + k];
        } else {
            const int c = k - 256;
            const float* p0 = ctx_part + (size_t)(2 * bb) * 256 + c;
            const float* p1 = ctx_part + (size_t)(2 * bb + 1) * 256 + c;
            float4 a0 = *(const float4*)p0, a1 = *(const float4*)(p0 + 4);
            float4 b0 = *(const float4*)p1, b1 = *(const float4*)(p1 + 4);
            us8 v;
            v[0]=f2bf((a0.x+b0.x)*inv); v[1]=f2bf((a0.y+b0.y)*inv);
            v[2]=f2bf((a0.z+b0.z)*inv); v[3]=f2bf((a0.w+b0.w)*inv);
            v[4]=f2bf((a1.x+b1.x)*inv); v[5]=f2bf((a1.y+b1.y)*inv);
            v[6]=f2bf((a1.z+b1.z)*inv); v[7]=f2bf((a1.w+b1.w)*inv);
            *(us8*)&As[sm * TS + sk8] = v;
        }
        *(us8*)&Bs[sm * TS + sk8] = cvt8(W3 + (n0 + sm) * 512 + k);
        __syncthreads();
        bf16x8 a = __builtin_bit_cast(bf16x8, *(const us8*)&As[(w * 16 + l15) * TS + quad * 8]);
        #pragma unroll
        for (int nt = 0; nt < 4; nt++) {
            bf16x8 b = __builtin_bit_cast(bf16x8, *(const us8*)&Bs[(nt * 16 + l15) * TS + quad * 8]);
            acc[nt] = __builtin_amdgcn_mfma_f32_16x16x32_bf16(a, b, acc[nt], 0, 0, 0);
        }
        __syncthreads();
    }
    #pragma unroll
    for (int nt = 0; nt < 4; nt++)
        #pragma unroll
        for (int r = 0; r < 4; r++) {
            int row = m0 + w * 16 + quad * 4 + r, col = n0 + nt * 16 + l15;
            float o = tanh_fast(acc[nt][r]);
            out[2 * B_ * H_ + row * 256 + col] = o;   // o_new
            A4u[row * 256 + col] = f2bf(o);
        }
}

// ------------------------------------------------- K6: logit = softmax(o_new @ W_out^T), grid 4
__global__ __launch_bounds__(256) void k_logit(
    const unsigned short* __restrict__ A4u, const float* __restrict__ W_out,
    float* __restrict__ out)
{
    const int m0 = blockIdx.x * 64;
    const int tid = threadIdx.x;
    const int w = tid >> 6, lane = tid & 63, quad = lane >> 4, l15 = lane & 15;
    __shared__ __align__(16) unsigned short As[64 * TS];
    __shared__ __align__(16) unsigned short Bs[192 * TS];
    __shared__ float lg[64][196];
    f32x4 acc[12];
    #pragma unroll
    for (int nt = 0; nt < 12; nt++) acc[nt] = (f32x4){0,0,0,0};
    const int sm = tid >> 2, sk8 = (tid & 3) * 8;
    for (int kc = 0; kc < 8; kc++) {
        const int k = kc * 32 + sk8;
        *(us8*)&As[sm * TS + sk8] = *(const us8*)&A4u[(m0 + sm) * 256 + k];
        #pragma unroll
        for (int rr = 0; rr < 3; rr++) {
            int j = rr * 64 + sm;
            us8 v = {0,0,0,0,0,0,0,0};
            if (j < OUT_) v = cvt8(W_out + j * 256 + k);
            *(us8*)&Bs[j * TS + sk8] = v;
        }
        __syncthreads();
        bf16x8 a = __builtin_bit_cast(bf16x8, *(const us8*)&As[(w * 16 + l15) * TS + quad * 8]);
        #pragma unroll
        for (int nt = 0; nt < 12; nt++) {
            bf16x8 b = __builtin_bit_cast(bf16x8, *(const us8*)&Bs[(nt * 16 + l15) * TS + quad * 8]);
            acc[nt] = __builtin_amdgcn_mfma_f32_16x16x32_bf16(a, b, acc[nt], 0, 0, 0);
        }
        __syncthreads();
    }
    #pragma unroll
    for (int nt = 0; nt < 12; nt++)
        #pragma unroll
        for (int r = 0; r < 4; r++)
            lg[w * 16 + quad * 4 + r][nt * 16 + l15] = acc[nt][r];
    __syncthreads();
    const int m = tid >> 2, p = tid & 3;
    const int cb = p * 43;
    float mx = -1e30f;
    for (int c = 0; c < 43; c++) mx = fmaxf(mx, lg[m][cb + c]);
    mx = fmaxf(mx, __shfl_xor(mx, 1));
    mx = fmaxf(mx, __shfl_xor(mx, 2));
    float s = 0.f;
    for (int c = 0; c < 43; c++) { float e = __expf(lg[m][cb + c] - mx); lg[m][cb + c] = e; s += e; }
    s += __shfl_xor(s, 1);
    s += __shfl_xor(s, 2);
    float inv = 1.f / s;
    for (int c = 0; c < 43; c++)
        out[3 * B_ * H_ + (m0 + m) * OUT_ + cb + c] = lg[m][cb + c] * inv;
}

// ------------------------------------------------- host
extern "C" void kernel_launch(void* const* d_in, const int* in_sizes, int n_in,
                              void* d_out, int out_size, void* d_ws, size_t ws_size,
                              hipStream_t stream)
{
    const float* h0   = (const float*)d_in[0];
    const float* c0   = (const float*)d_in[1];
    const float* o_t  = (const float*)d_in[2];
    const float* enc  = (const float*)d_in[3];
    const int*   lt   = (const int*)  d_in[4];
    const float* emb  = (const float*)d_in[5];
    const float* W_ih = (const float*)d_in[6];
    const float* W_hh = (const float*)d_in[7];
    const float* b_ih = (const float*)d_in[8];
    const float* b_hh = (const float*)d_in[9];
    const float* W1   = (const float*)d_in[10];
    const float* W2   = (const float*)d_in[11];
    const float* W3   = (const float*)d_in[12];
    const float* Wo   = (const float*)d_in[13];
    const float* beta = (const float*)d_in[14];
    float* out = (float*)d_out;
    float* ws  = (float*)d_ws;

    float*          gates    = ws;                               // 256*1024 f32
    float*          hW2      = ws + 262144;                      // 256*256 f32
    float*          ctx_part = ws + 327680;                      // 512*256 f32
    float*          s_part   = ws + 458752;                      // 512 f32
    unsigned short* A3u      = (unsigned short*)(ws + 459264);   // 256*256 bf16 (h)
    unsigned short* A4u      = (unsigned short*)(ws + 492032);   // 256*256 bf16 (o_new)

    k_gates<<<64, 256, 0, stream>>>(h0, o_t, lt, emb, W_ih, W_hh, b_ih, b_hh, gates);
    k_lstm <<<256, 256, 0, stream>>>(gates, c0, out, A3u);
    k_hw2  <<<16, 256, 0, stream>>>(A3u, W2, hW2);
    k_attn <<<512, 512, 0, stream>>>(enc, W1, hW2, beta, ctx_part, s_part);
    k_out3 <<<16, 256, 0, stream>>>(A3u, ctx_part, s_part, W3, out, A4u);
    k_logit<<<4, 256, 0, stream>>>(A4u, Wo, out);
}